// Round 3
// baseline (141.967 us; speedup 1.0000x reference)
//
#include <hip/hip_runtime.h>

#define BLOCK 256
#define GRID 2048
#define UNROLL 8

__global__ __launch_bounds__(BLOCK) void wbce_reduce_kernel(
    const float* __restrict__ x, const int* __restrict__ t,
    long long n, double* __restrict__ ws) {
    const int n4 = (int)(n >> 2);
    const int tid = threadIdx.x;

    // block-contiguous partition: each block owns iters_total chunks of
    // BLOCK*UNROLL float4's, laid out contiguously (page/TLB friendly)
    const int per_iter = BLOCK * UNROLL;                 // float4's per chunk
    const int iters_total = n4 / (GRID * per_iter);      // full chunks per block
    const int main_count = GRID * per_iter * iters_total;

    float tot = 0.0f, pos = 0.0f;   // sums of -log2(a); scaled by ln2 at the end
    int cnt = 0;

    const float4* __restrict__ x4 = (const float4*)x;
    const int4*   __restrict__ t4 = (const int4*)t;

#define PROC(XC, TC)                                        \
    {                                                       \
        float xi = (XC); int ti = (TC);                     \
        float a = ti ? xi : (1.0f - xi);                    \
        float v = -__log2f(a);                              \
        tot += v;                                           \
        pos += ti ? v : 0.0f;                               \
        cnt += ti;                                          \
    }

    int base = blockIdx.x * per_iter * iters_total + tid;
    for (int it = 0; it < iters_total; ++it, base += per_iter) {
        float4 xv[UNROLL];
        int4   tv[UNROLL];
#pragma unroll
        for (int j = 0; j < UNROLL; ++j)
            xv[j] = x4[base + j * BLOCK];
#pragma unroll
        for (int j = 0; j < UNROLL; ++j)
            tv[j] = t4[base + j * BLOCK];
#pragma unroll
        for (int j = 0; j < UNROLL; ++j) {
            PROC(xv[j].x, tv[j].x)
            PROC(xv[j].y, tv[j].y)
            PROC(xv[j].z, tv[j].z)
            PROC(xv[j].w, tv[j].w)
        }
    }

    // remainder of float4-aligned region (grid-stride)
    for (int i = main_count + blockIdx.x * BLOCK + tid; i < n4; i += GRID * BLOCK) {
        float4 xv = x4[i];
        int4   tv = t4[i];
        PROC(xv.x, tv.x)
        PROC(xv.y, tv.y)
        PROC(xv.z, tv.z)
        PROC(xv.w, tv.w)
    }

    // scalar tail (n not divisible by 4) — block 0 thread 0
    if (blockIdx.x == 0 && tid == 0) {
        for (long long i = (long long)n4 << 2; i < n; ++i) {
            float xi = x[i]; int ti = t[i];
            float a = ti ? xi : (1.0f - xi);
            float v = -__log2f(a);
            tot += v;
            pos += ti ? v : 0.0f;
            cnt += ti;
        }
    }
#undef PROC

    float neg = tot - pos;

    // wave reduction (64 lanes)
    for (int o = 32; o > 0; o >>= 1) {
        pos += __shfl_down(pos, o);
        neg += __shfl_down(neg, o);
        cnt += __shfl_down(cnt, o);
    }

    __shared__ float s_pos[BLOCK / 64];
    __shared__ float s_neg[BLOCK / 64];
    __shared__ int   s_cnt[BLOCK / 64];
    const int lane = tid & 63;
    const int wave = tid >> 6;
    if (lane == 0) {
        s_pos[wave] = pos;
        s_neg[wave] = neg;
        s_cnt[wave] = cnt;
    }
    __syncthreads();

    if (tid == 0) {
        double bpos = 0.0, bneg = 0.0;
        long long bcnt = 0;
        for (int w = 0; w < BLOCK / 64; ++w) {
            bpos += (double)s_pos[w];
            bneg += (double)s_neg[w];
            bcnt += s_cnt[w];
        }
        atomicAdd(&ws[0], (double)bcnt);
        atomicAdd(&ws[1], bpos);
        atomicAdd(&ws[2], bneg);
    }
}

__global__ void wbce_finalize_kernel(const double* __restrict__ ws,
                                     float* __restrict__ out, double n) {
    const double LN2 = 0.6931471805599453;
    double s   = ws[0];
    double pos = ws[1] * LN2;   // sums were in log2 units
    double neg = ws[2] * LN2;
    double len = n + 1.0;
    double wp  = len / (s + 1.0);
    double wn  = len / (len - s);
    double loss = ((wp + 1.0) * pos + (wn + 1.0) * neg) / n;
    out[0] = (float)loss;
}

extern "C" void kernel_launch(void* const* d_in, const int* in_sizes, int n_in,
                              void* d_out, int out_size, void* d_ws, size_t ws_size,
                              hipStream_t stream) {
    const float* x = (const float*)d_in[0];
    const int*   t = (const int*)d_in[1];
    float* out = (float*)d_out;
    double* ws = (double*)d_ws;
    const long long n = (long long)in_sizes[0];

    hipMemsetAsync(ws, 0, 3 * sizeof(double), stream);
    wbce_reduce_kernel<<<GRID, BLOCK, 0, stream>>>(x, t, n, ws);
    wbce_finalize_kernel<<<1, 1, 0, stream>>>(ws, out, (double)n);
}